// Round 5
// baseline (352.098 us; speedup 1.0000x reference)
//
#include <hip/hip_runtime.h>
#include <math.h>

// Problem constants
#define N_Q    32768
#define N_E    262144
// dims: IN=EMB=192, concat=384, 2*HID=384, BOT=192, PREDH=192, OUT=4
//
// Factorization: layer0 of the edge MLP is linear in the concat ->
//   h0(e) = gelu( pg[gidx(e)] + pq[qidx(e)] )
//   pg = x @ (proj_w @ W0_top) + (proj_b @ W0_top + msg0_b)   (per grid point)
//   pq = sincos(qpos) @ W0_bot                                 (per query)

typedef _Float16 half8 __attribute__((ext_vector_type(8)));
typedef _Float16 half4v __attribute__((ext_vector_type(4)));
typedef float f32x4 __attribute__((ext_vector_type(4)));
typedef float f32x16 __attribute__((ext_vector_type(16)));

// A&S 7.1.25 erf (|eps|<=2.5e-5, invisible under f16 storage rounding 5e-4).
__device__ __forceinline__ float gelu_f(float x) {
    float ax = fabsf(x);
    float t = __builtin_amdgcn_rcpf(fmaf(0.33269070724668f, ax, 1.0f));
    float poly = t * fmaf(t, fmaf(t, 0.7478556f, -0.0958798f), 0.3480242f);
    float e = exp2f(-0.72134752044448f * ax * ax);
    float u = fmaf(-poly, e, 1.0f);          // erf(z)
    return 0.5f * fmaf(ax, u, x);
}

// ---------------- pack W[K][N] fp32 -> fragment-order f16 (16x16x32 format) ----------
// Per (n_tile16, ks32) a 1KB block; lane l holds W[k=ks*32+(l>>4)*8+j][n=nt*16+(l&15)]
__device__ __forceinline__ void pack_one(const float* __restrict__ W,
                                         _Float16* __restrict__ Wp,
                                         int K, int N, int blk0, int tid) {
    int u = blk0 * 256 + tid;                   // one half8 per thread
    if (u * 8 >= K * N) return;
    int l = u & 63, blk = u >> 6;
    int nks = K >> 5;
    int ntile = blk / nks, ks = blk - ntile * nks;
    int n = ntile * 16 + (l & 15);
    int k0 = ks * 32 + (l >> 4) * 8;
    half8 v;
    #pragma unroll
    for (int j = 0; j < 8; ++j) v[j] = (_Float16)W[(size_t)(k0 + j) * N + n];
    *(half8*)(Wp + (size_t)u * 8) = v;
}

// ---------------- pack W[K][N] fp32 -> fragment-order f16 (32x32x16 format) ----------
// Per (n_tile32, ks16) a 1KB block; lane l holds W[k=ks*16+(l>>5)*8+j][n=nt*32+(l&31)]
__device__ __forceinline__ void pack32_one(const float* __restrict__ W,
                                           _Float16* __restrict__ Wp,
                                           int K, int N, int blk0, int tid) {
    int u = blk0 * 256 + tid;
    if (u * 8 >= K * N) return;
    int l = u & 63, blk = u >> 6;
    int nks = K >> 4;
    int ntile = blk / nks, ks = blk - ntile * nks;
    int n = ntile * 32 + (l & 31);
    int k0 = ks * 16 + (l >> 5) * 8;
    half8 v;
    #pragma unroll
    for (int j = 0; j < 8; ++j) v[j] = (_Float16)W[(size_t)(k0 + j) * N + n];
    *(half8*)(Wp + (size_t)u * 8) = v;
}

// ---------------- fused prep (Wc -> WpC fragments directly, bc) + pack of 4 mats -----
__global__ __launch_bounds__(256, 4) void preppack_kernel(
    const float* __restrict__ proj_w, const float* __restrict__ proj_b,
    const float* __restrict__ msg0_w, const float* __restrict__ msg0_b,
    const float* __restrict__ msg1_w, const float* __restrict__ msg2_w,
    const float* __restrict__ pred0_w,
    _Float16* __restrict__ WpC, float* __restrict__ bc,
    _Float16* __restrict__ WpQ, _Float16* __restrict__ Wp1,
    _Float16* __restrict__ Wp2, _Float16* __restrict__ WpH)
{
    int b = blockIdx.x, t = threadIdx.x;
    if (b < 290) {                               // prep: Wc = proj_w @ W0_top, + bc
        int gid = b * 256 + t;
        if (gid < 73728) {                       // 192*384
            int j = gid / 384, n = gid - j * 384;
            float a = 0.0f;
            for (int k = 0; k < 192; ++k)
                a = fmaf(proj_w[j * 192 + k], msg0_w[k * 384 + n], a);
            // write directly into fragment position of WpC (16x16 pack, K=192, N=384)
            int off = (((n >> 4) * 6 + (j >> 5)) * 512) +
                      ((((j >> 3) & 3) * 16 + (n & 15)) * 8) + (j & 7);
            WpC[off] = (_Float16)a;
        } else if (gid < 73728 + 384) {
            int n = gid - 73728;
            float a = msg0_b[n];
            for (int k = 0; k < 192; ++k)
                a = fmaf(proj_b[k], msg0_w[k * 384 + n], a);
            bc[n] = a;
        }
    } else {
        int p = b - 290;                          // 162 pack blocks
        if      (p < 36)  pack_one  (msg0_w + 73728, WpQ, 192, 384, p,       t); // W0_bot
        else if (p < 108) pack32_one(msg1_w,         Wp1, 384, 384, p - 36,  t); // 32x32
        else if (p < 144) pack_one  (msg2_w,         Wp2, 384, 192, p - 108, t);
        else              pack_one  (pred0_w,        WpH, 192, 192, p - 144, t);
    }
}

// ---------------- pg/pq fused (+ seg/cnt zeroing blocks), 32-row tiles ---------------
// pg = x @ WpC + bc ; pq = sincos(qpos) @ WpQ. lane holds out[m=ln][n=base+lq*4+r]
#define PK 200   // hA row stride (f16), 400 B

__global__ __launch_bounds__(256, 4) void pgpq_kernel(
    const float* __restrict__ x, const float* __restrict__ qpos,
    const _Float16* __restrict__ WpC, const _Float16* __restrict__ WpQ,
    const float* __restrict__ bc,
    _Float16* __restrict__ pg, _Float16* __restrict__ pq,
    float* __restrict__ seg)
{
    __shared__ _Float16 hA[32 * PK];   // 12800 B
    const int t = threadIdx.x;

    if (blockIdx.x >= 2048) {          // zero seg (25165824 B) + cnt (131072 B)
        float4* dst = (float4*)seg + (size_t)(blockIdx.x - 2048) * 4096 + t;
        #pragma unroll
        for (int i = 0; i < 16; ++i) dst[i * 256] = (float4){0.f, 0.f, 0.f, 0.f};
        return;
    }

    const bool isPg = blockIdx.x < 1024;
    const int r0 = (isPg ? blockIdx.x : blockIdx.x - 1024) * 32;
    const int lane = t & 63;
    const int w = t >> 6;
    const int ln = lane & 15, lq = lane >> 4;

    if (isPg) {
        #pragma unroll
        for (int i = 0; i < 6; ++i) {                 // 1536 float4s
            int idx = t + 256 * i;
            int r = idx / 48, c4 = idx - r * 48;
            float4 v = ((const float4*)(x + (size_t)(r0 + r) * 192))[c4];
            half4v hv; hv[0] = (_Float16)v.x; hv[1] = (_Float16)v.y;
            hv[2] = (_Float16)v.z; hv[3] = (_Float16)v.w;
            *(half4v*)(hA + r * PK + c4 * 4) = hv;
        }
    } else {
        #pragma unroll
        for (int it = 0; it < 12; ++it) {             // 3072 = 32*96 sin/cos pairs
            int g2 = t + 256 * it;
            int r = g2 / 96, rem = g2 - r * 96;
            int d = rem >> 5, i = rem & 31;
            float omega = exp2f(-(float)i * 0.41524101186092029f);  // log2(1e4)/32
            float arg = qpos[(size_t)(r0 + r) * 3 + d] * omega;
            float rev = arg * 0.15915494309189535f;
            rev = rev - floorf(rev);
            hA[r * PK + d * 64 + i]      = (_Float16)__builtin_amdgcn_sinf(rev);
            hA[r * PK + d * 64 + 32 + i] = (_Float16)__builtin_amdgcn_cosf(rev);
        }
    }
    __syncthreads();

    const _Float16* __restrict__ Wp = isPg ? WpC : WpQ;
    _Float16* __restrict__ out = isPg ? pg : pq;

    f32x4 acc[2][6];
    #pragma unroll
    for (int nt = 0; nt < 6; ++nt) {
        f32x4 bv = isPg ? *(const f32x4*)(bc + w * 96 + nt * 16 + lq * 4)
                        : (f32x4){0.f, 0.f, 0.f, 0.f};
        #pragma unroll
        for (int mt = 0; mt < 2; ++mt) acc[mt][nt] = bv;
    }
    #pragma unroll 2
    for (int ks = 0; ks < 6; ++ks) {
        half8 a[2], bf[6];
        #pragma unroll
        for (int mt = 0; mt < 2; ++mt)
            a[mt] = *(const half8*)(hA + (mt * 16 + ln) * PK + ks * 32 + lq * 8);
        #pragma unroll
        for (int nt = 0; nt < 6; ++nt)
            bf[nt] = *(const half8*)(Wp + (size_t)(((w * 6 + nt) * 6 + ks) * 512 + lane * 8));
        #pragma unroll
        for (int nt = 0; nt < 6; ++nt)
            #pragma unroll
            for (int mt = 0; mt < 2; ++mt)
                acc[mt][nt] = __builtin_amdgcn_mfma_f32_16x16x32_f16(bf[nt], a[mt], acc[mt][nt], 0, 0, 0);
    }
    #pragma unroll
    for (int mt = 0; mt < 2; ++mt)
        #pragma unroll
        for (int nt = 0; nt < 6; ++nt) {
            half4v hv;
            #pragma unroll
            for (int r = 0; r < 4; ++r) hv[r] = (_Float16)acc[mt][nt][r];
            *(half4v*)(out + (size_t)(r0 + mt * 16 + ln) * 384 + w * 96 + nt * 16 + lq * 4) = hv;
        }
}

// ---------------- fused edge MLP (layers 1,2) via f16 MFMA, 512 thr / 8 waves --------
// L1 uses 32x32x16 MFMA (2x FLOP/instr); L2 stays 16x16x32.
#define PADK 392   // hA row stride in f16 elements (784 B)
#define H2S  196   // h2 (f32 view) row stride; conflict-free b128

__global__ __launch_bounds__(512, 6) void edge_mlp_kernel(
    const _Float16* __restrict__ pg, const _Float16* __restrict__ pq,
    const int* __restrict__ edges,
    const _Float16* __restrict__ Wp1, const float* __restrict__ b1,
    const _Float16* __restrict__ Wp2, const float* __restrict__ b2,
    float* __restrict__ seg, float* __restrict__ cnt)
{
    __shared__ _Float16 hA[64 * PADK];   // 50176 B; aliased as f32 h2[64][H2S] later
    __shared__ int qi[64];
    float* h2 = (float*)hA;

    const int t = threadIdx.x;
    const int e0 = blockIdx.x * 64;
    const int lane = t & 63;
    const int w = t >> 6;                // 0..7
    const int ln = lane & 15;
    const int lq = lane >> 4;

    if (t < 64) qi[t] = edges[2 * (e0 + t)];

    // ---- gather h0 = gelu(pg[g] + pq[q]); thread t owns edge m=t>>3, chunk lane t&7 --
    {
        const int m = t >> 3;            // 0..63
        const int cl = t & 7;
        int2 eg = ((const int2*)edges)[e0 + m];     // {qidx, gidx}
        const half8* gsrc = (const half8*)(pg + (size_t)eg.y * 384) + cl;
        const half8* qsrc = (const half8*)(pq + (size_t)eg.x * 384) + cl;
        half8* dst = (half8*)(hA + m * PADK + cl * 8);
        #pragma unroll
        for (int i = 0; i < 6; ++i) {
            half8 va = gsrc[i * 8];
            half8 vb = qsrc[i * 8];
            half8 o;
            #pragma unroll
            for (int j = 0; j < 8; ++j)
                o[j] = (_Float16)gelu_f((float)va[j] + (float)vb[j]);
            dst[i * 8] = o;
        }
    }
    __syncthreads();

    // ---- layer 1: 384 -> 384 via 32x32x16, gelu, in-place. 2m x 4n wave grid ----
    // mfma32(Wfrag, hfrag) = (h@W)^T: lane holds out[m=l&31][n = base+(r&3)+8*(r>>2)+4*(l>>5)]
    {
        const int wm = w >> 2, wn = w & 3;
        const int l31 = lane & 31, lh = lane >> 5;
        const int cb = wn * 96;
        f32x16 acc[3];
        #pragma unroll
        for (int nt = 0; nt < 3; ++nt)
            #pragma unroll
            for (int g = 0; g < 4; ++g) {
                float4 bv = *(const float4*)(b1 + cb + nt * 32 + g * 8 + lh * 4);
                acc[nt][4 * g + 0] = bv.x; acc[nt][4 * g + 1] = bv.y;
                acc[nt][4 * g + 2] = bv.z; acc[nt][4 * g + 3] = bv.w;
            }
        #pragma unroll 4
        for (int ks = 0; ks < 24; ++ks) {
            half8 a = *(const half8*)(hA + (wm * 32 + l31) * PADK + ks * 16 + lh * 8);
            half8 bf[3];
            #pragma unroll
            for (int nt = 0; nt < 3; ++nt)
                bf[nt] = *(const half8*)(Wp1 + (size_t)(((wn * 3 + nt) * 24 + ks) * 512 + lane * 8));
            #pragma unroll
            for (int nt = 0; nt < 3; ++nt)
                acc[nt] = __builtin_amdgcn_mfma_f32_32x32x16_f16(bf[nt], a, acc[nt], 0, 0, 0);
        }
        __syncthreads();   // all waves done reading hA
        #pragma unroll
        for (int nt = 0; nt < 3; ++nt)
            #pragma unroll
            for (int g = 0; g < 4; ++g) {
                half4v hv;
                #pragma unroll
                for (int q = 0; q < 4; ++q) hv[q] = (_Float16)gelu_f(acc[nt][4 * g + q]);
                *(half4v*)(hA + (wm * 32 + l31) * PADK + cb + nt * 32 + g * 8 + lh * 4) = hv;
            }
        __syncthreads();
    }

    // ---- layer 2: 384 -> 192 via 16x16x32. wave w: n-slice (w&3)*48, m-half (w>>2)*32
    {
        const int n0 = (w & 3) * 48;
        const int mh = (w >> 2) * 2;                 // physical m-tile base
        f32x4 acc[2][3];
        #pragma unroll
        for (int nt = 0; nt < 3; ++nt) {
            f32x4 bv = *(const f32x4*)(b2 + n0 + nt * 16 + lq * 4);
            #pragma unroll
            for (int mt = 0; mt < 2; ++mt) acc[mt][nt] = bv;
        }
        #pragma unroll 2
        for (int ks = 0; ks < 12; ++ks) {
            half8 a[2], bf[3];
            #pragma unroll
            for (int mt = 0; mt < 2; ++mt)
                a[mt] = *(const half8*)(hA + ((mh + mt) * 16 + ln) * PADK + ks * 32 + lq * 8);
            #pragma unroll
            for (int nt = 0; nt < 3; ++nt)
                bf[nt] = *(const half8*)(Wp2 + (size_t)((((w & 3) * 3 + nt) * 12 + ks) * 512 + lane * 8));
            #pragma unroll
            for (int nt = 0; nt < 3; ++nt)
                #pragma unroll
                for (int mt = 0; mt < 2; ++mt)
                    acc[mt][nt] = __builtin_amdgcn_mfma_f32_16x16x32_f16(bf[nt], a[mt], acc[mt][nt], 0, 0, 0);
        }
        __syncthreads();   // all waves done reading hA; safe to overwrite as h2
        #pragma unroll
        for (int mt = 0; mt < 2; ++mt)
            #pragma unroll
            for (int nt = 0; nt < 3; ++nt)
                *(f32x4*)(h2 + ((mh + mt) * 16 + ln) * H2S + n0 + nt * 16 + lq * 4) = acc[mt][nt];
        __syncthreads();
    }

    // ---- segment reduce within block (qidx sorted), 2 row-halves, then atomics ----
    if (t < 384) {
        int half_ = t >= 192;
        int col = t - half_ * 192;
        int mlo = half_ * 32, mhi = mlo + 32;
        float a = 0.0f;
        for (int m = mlo; m < mhi; ++m) {
            a += h2[m * H2S + col];
            if (m == mhi - 1 || qi[m + 1] != qi[m]) {
                atomicAdd(&seg[(size_t)qi[m] * 192 + col], a);
                a = 0.0f;
            }
        }
    } else if (t < 386) {
        int half_ = t - 384;
        int mlo = half_ * 32, mhi = mlo + 32;
        float run = 1.0f;
        for (int m = mlo + 1; m < mhi; ++m) {
            if (qi[m] != qi[m - 1]) { atomicAdd(&cnt[qi[m - 1]], run); run = 1.0f; }
            else run += 1.0f;
        }
        atomicAdd(&cnt[qi[mhi - 1]], run);
    }
}

// ---------------- head: m = seg/max(cnt,1); out = gelu(m@W0+b0)@W1+b1 ----------------
#define PSK 196   // ps row stride (f32)

__global__ __launch_bounds__(256, 3) void head_kernel(
    const float* __restrict__ seg, const float* __restrict__ cnt,
    const _Float16* __restrict__ Wp0, const float* __restrict__ b0,
    const float* __restrict__ w1, const float* __restrict__ b1,
    float* __restrict__ out)
{
    __shared__ _Float16 hA[32 * PK];     // 12800 B
    __shared__ float ps[32 * PSK];       // 25088 B
    __shared__ float w1s[192 * 4];
    __shared__ float invc[32];
    const int t = threadIdx.x;
    const int r0 = blockIdx.x * 32;
    const int lane = t & 63;
    const int w = t >> 6;
    const int ln = lane & 15, lq = lane >> 4;

    if (t < 32) invc[t] = 1.0f / fmaxf(cnt[r0 + t], 1.0f);
    if (t < 192) ((float4*)w1s)[t] = ((const float4*)w1)[t];
    __syncthreads();

    #pragma unroll
    for (int i = 0; i < 6; ++i) {                    // 1536 float4s
        int idx = t + 256 * i;
        int r = idx / 48, c4 = idx - r * 48;
        float inv = invc[r];
        float4 v = ((const float4*)(seg + (size_t)(r0 + r) * 192))[c4];
        half4v hv; hv[0] = (_Float16)(v.x * inv); hv[1] = (_Float16)(v.y * inv);
        hv[2] = (_Float16)(v.z * inv); hv[3] = (_Float16)(v.w * inv);
        *(half4v*)(hA + r * PK + c4 * 4) = hv;
    }
    __syncthreads();

    f32x4 acc[2][3];
    #pragma unroll
    for (int nt = 0; nt < 3; ++nt) {
        f32x4 bv = *(const f32x4*)(b0 + w * 48 + nt * 16 + lq * 4);
        #pragma unroll
        for (int mt = 0; mt < 2; ++mt) acc[mt][nt] = bv;
    }
    #pragma unroll 2
    for (int ks = 0; ks < 6; ++ks) {
        half8 a[2], bf[3];
        #pragma unroll
        for (int mt = 0; mt < 2; ++mt)
            a[mt] = *(const half8*)(hA + (mt * 16 + ln) * PK + ks * 32 + lq * 8);
        #pragma unroll
        for (int nt = 0; nt < 3; ++nt)
            bf[nt] = *(const half8*)(Wp0 + (size_t)(((w * 3 + nt) * 6 + ks) * 512 + lane * 8));
        #pragma unroll
        for (int nt = 0; nt < 3; ++nt)
            #pragma unroll
            for (int mt = 0; mt < 2; ++mt)
                acc[mt][nt] = __builtin_amdgcn_mfma_f32_16x16x32_f16(bf[nt], a[mt], acc[mt][nt], 0, 0, 0);
    }
    // lane holds ps[m = mt*16+ln][n = w*48 + nt*16 + lq*4 + r] -> b128 LDS writes
    #pragma unroll
    for (int mt = 0; mt < 2; ++mt)
        #pragma unroll
        for (int nt = 0; nt < 3; ++nt) {
            f32x4 g;
            #pragma unroll
            for (int r = 0; r < 4; ++r) g[r] = gelu_f(acc[mt][nt][r]);
            *(f32x4*)(ps + (mt * 16 + ln) * PSK + w * 48 + nt * 16 + lq * 4) = g;
        }
    __syncthreads();

    // layer1: 192 -> 4, one thread per (row, out-col); rows 0..31
    if (t < 128) {
        int r = t >> 2, oo = t & 3;
        float a = b1[oo];
        for (int k = 0; k < 192; ++k)
            a = fmaf(ps[r * PSK + k], w1s[k * 4 + oo], a);
        out[(size_t)(r0 + r) * 4 + oo] = a;
    }
}

extern "C" void kernel_launch(void* const* d_in, const int* in_sizes, int n_in,
                              void* d_out, int out_size, void* d_ws, size_t ws_size,
                              hipStream_t stream) {
    (void)in_sizes; (void)n_in; (void)out_size; (void)ws_size;
    const float* x       = (const float*)d_in[0];
    const float* qpos    = (const float*)d_in[1];
    const int*   edges   = (const int*)d_in[2];
    const float* proj_w  = (const float*)d_in[3];
    const float* proj_b  = (const float*)d_in[4];
    const float* msg0_w  = (const float*)d_in[5];
    const float* msg0_b  = (const float*)d_in[6];
    const float* msg1_w  = (const float*)d_in[7];
    const float* msg1_b  = (const float*)d_in[8];
    const float* msg2_w  = (const float*)d_in[9];
    const float* msg2_b  = (const float*)d_in[10];
    const float* pred0_w = (const float*)d_in[11];
    const float* pred0_b = (const float*)d_in[12];
    const float* pred1_w = (const float*)d_in[13];
    const float* pred1_b = (const float*)d_in[14];
    float* out = (float*)d_out;

    // ws layout (bytes):
    //  pg  f16: 25165824  @ 0
    //  pq  f16: 25165824  @ 25165824
    //  seg f32: 25165824  @ 50331648
    //  cnt f32:   131072  @ 75497472   (seg+cnt zeroed by pgpq zero-blocks)
    //  bc  f32:     1536  @ 75628544
    //  WpC f16:   147456  @ 75630080
    //  WpQ f16:   147456  @ 75777536
    //  Wp1 f16:   294912  @ 75924992   (32x32 pack)
    //  Wp2 f16:   147456  @ 76219904
    //  WpH f16:    73728  @ 76367360   (end 76441088)
    char* ws = (char*)d_ws;
    _Float16* pg  = (_Float16*)(ws);
    _Float16* pq  = (_Float16*)(ws + 25165824);
    float*    seg = (float*)(ws + 50331648);
    float*    cnt = (float*)(ws + 75497472);
    float*    bc  = (float*)(ws + 75628544);
    _Float16* WpC = (_Float16*)(ws + 75630080);
    _Float16* WpQ = (_Float16*)(ws + 75777536);
    _Float16* Wp1 = (_Float16*)(ws + 75924992);
    _Float16* Wp2 = (_Float16*)(ws + 76219904);
    _Float16* WpH = (_Float16*)(ws + 76367360);

    preppack_kernel<<<452, 256, 0, stream>>>(proj_w, proj_b, msg0_w, msg0_b,
                                             msg1_w, msg2_w, pred0_w,
                                             WpC, bc, WpQ, Wp1, Wp2, WpH);
    // 2048 GEMM blocks + 386 zero-blocks (25296896 B = seg+cnt, 65536 B each)
    pgpq_kernel<<<2434, 256, 0, stream>>>(x, qpos, WpC, WpQ, bc, pg, pq, seg);
    edge_mlp_kernel<<<4096, 512, 0, stream>>>(pg, pq, edges,
                                              Wp1, msg1_b, Wp2, msg2_b,
                                              seg, cnt);
    head_kernel<<<1024, 256, 0, stream>>>(seg, cnt, WpH, pred0_b,
                                          pred1_w, pred1_b, out);
}

// Round 6
// 327.485 us; speedup vs baseline: 1.0752x; 1.0752x over previous
//
#include <hip/hip_runtime.h>
#include <math.h>

// Problem constants
#define N_Q    32768
#define N_E    262144
// dims: IN=EMB=192, concat=384, 2*HID=384, BOT=192, PREDH=192, OUT=4
//
// Factorization: layer0 of the edge MLP is linear in the concat ->
//   h0(e) = gelu( pg[gidx(e)] + pq[qidx(e)] )
//   pg = x @ (proj_w @ W0_top) + (proj_b @ W0_top + msg0_b)   (per grid point)
//   pq = sincos(qpos) @ W0_bot                                 (per query)

typedef _Float16 half8 __attribute__((ext_vector_type(8)));
typedef _Float16 half4v __attribute__((ext_vector_type(4)));
typedef float f32x4 __attribute__((ext_vector_type(4)));

// A&S 7.1.25 erf (|eps|<=2.5e-5, invisible under f16 storage rounding 5e-4).
__device__ __forceinline__ float gelu_f(float x) {
    float ax = fabsf(x);
    float t = __builtin_amdgcn_rcpf(fmaf(0.33269070724668f, ax, 1.0f));
    float poly = t * fmaf(t, fmaf(t, 0.7478556f, -0.0958798f), 0.3480242f);
    float e = exp2f(-0.72134752044448f * ax * ax);
    float u = fmaf(-poly, e, 1.0f);          // erf(z)
    return 0.5f * fmaf(ax, u, x);
}

// ---------------- pack W[K][N] fp32 -> fragment-order f16 (16x16x32 format) ----------
// Per (n_tile16, ks32) a 1KB block; lane l holds W[k=ks*32+(l>>4)*8+j][n=nt*16+(l&15)]
__device__ __forceinline__ void pack_one(const float* __restrict__ W,
                                         _Float16* __restrict__ Wp,
                                         int K, int N, int blk0, int tid) {
    int u = blk0 * 256 + tid;                   // one half8 per thread
    if (u * 8 >= K * N) return;
    int l = u & 63, blk = u >> 6;
    int nks = K >> 5;
    int ntile = blk / nks, ks = blk - ntile * nks;
    int n = ntile * 16 + (l & 15);
    int k0 = ks * 32 + (l >> 4) * 8;
    half8 v;
    #pragma unroll
    for (int j = 0; j < 8; ++j) v[j] = (_Float16)W[(size_t)(k0 + j) * N + n];
    *(half8*)(Wp + (size_t)u * 8) = v;
}

// ---------------- fused prep (Wc -> WpC fragments directly, bc) + pack of 4 mats -----
__global__ __launch_bounds__(256, 4) void preppack_kernel(
    const float* __restrict__ proj_w, const float* __restrict__ proj_b,
    const float* __restrict__ msg0_w, const float* __restrict__ msg0_b,
    const float* __restrict__ msg1_w, const float* __restrict__ msg2_w,
    const float* __restrict__ pred0_w,
    _Float16* __restrict__ WpC, float* __restrict__ bc,
    _Float16* __restrict__ WpQ, _Float16* __restrict__ Wp1,
    _Float16* __restrict__ Wp2, _Float16* __restrict__ WpH)
{
    int b = blockIdx.x, t = threadIdx.x;
    if (b < 290) {                               // prep: Wc = proj_w @ W0_top, + bc
        int gid = b * 256 + t;
        if (gid < 73728) {                       // 192*384
            int j = gid / 384, n = gid - j * 384;
            float a = 0.0f;
            for (int k = 0; k < 192; ++k)
                a = fmaf(proj_w[j * 192 + k], msg0_w[k * 384 + n], a);
            // write directly into fragment position of WpC (16x16 pack, K=192, N=384)
            int off = (((n >> 4) * 6 + (j >> 5)) * 512) +
                      ((((j >> 3) & 3) * 16 + (n & 15)) * 8) + (j & 7);
            WpC[off] = (_Float16)a;
        } else if (gid < 73728 + 384) {
            int n = gid - 73728;
            float a = msg0_b[n];
            for (int k = 0; k < 192; ++k)
                a = fmaf(proj_b[k], msg0_w[k * 384 + n], a);
            bc[n] = a;
        }
    } else {
        int p = b - 290;                          // 162 pack blocks
        if      (p < 36)  pack_one(msg0_w + 73728, WpQ, 192, 384, p,       t); // W0_bot
        else if (p < 108) pack_one(msg1_w,         Wp1, 384, 384, p - 36,  t);
        else if (p < 144) pack_one(msg2_w,         Wp2, 384, 192, p - 108, t);
        else              pack_one(pred0_w,        WpH, 192, 192, p - 144, t);
    }
}

// ---------------- pg/pq fused (+ seg/cnt zeroing blocks), 32-row tiles ---------------
// pg = x @ WpC + bc ; pq = sincos(qpos) @ WpQ. lane holds out[m=ln][n=base+lq*4+r]
#define PK 200   // hA row stride (f16), 400 B

__global__ __launch_bounds__(256, 4) void pgpq_kernel(
    const float* __restrict__ x, const float* __restrict__ qpos,
    const _Float16* __restrict__ WpC, const _Float16* __restrict__ WpQ,
    const float* __restrict__ bc,
    _Float16* __restrict__ pg, _Float16* __restrict__ pq,
    float* __restrict__ seg)
{
    __shared__ _Float16 hA[32 * PK];   // 12800 B
    const int t = threadIdx.x;

    if (blockIdx.x >= 2048) {          // zero seg (25165824 B) + cnt (131072 B)
        float4* dst = (float4*)seg + (size_t)(blockIdx.x - 2048) * 4096 + t;
        #pragma unroll
        for (int i = 0; i < 16; ++i) dst[i * 256] = (float4){0.f, 0.f, 0.f, 0.f};
        return;
    }

    const bool isPg = blockIdx.x < 1024;
    const int r0 = (isPg ? blockIdx.x : blockIdx.x - 1024) * 32;
    const int lane = t & 63;
    const int w = t >> 6;
    const int ln = lane & 15, lq = lane >> 4;

    if (isPg) {
        #pragma unroll
        for (int i = 0; i < 6; ++i) {                 // 1536 float4s
            int idx = t + 256 * i;
            int r = idx / 48, c4 = idx - r * 48;
            float4 v = ((const float4*)(x + (size_t)(r0 + r) * 192))[c4];
            half4v hv; hv[0] = (_Float16)v.x; hv[1] = (_Float16)v.y;
            hv[2] = (_Float16)v.z; hv[3] = (_Float16)v.w;
            *(half4v*)(hA + r * PK + c4 * 4) = hv;
        }
    } else {
        #pragma unroll
        for (int it = 0; it < 12; ++it) {             // 3072 = 32*96 sin/cos pairs
            int g2 = t + 256 * it;
            int r = g2 / 96, rem = g2 - r * 96;
            int d = rem >> 5, i = rem & 31;
            float omega = exp2f(-(float)i * 0.41524101186092029f);  // log2(1e4)/32
            float arg = qpos[(size_t)(r0 + r) * 3 + d] * omega;
            float rev = arg * 0.15915494309189535f;
            rev = rev - floorf(rev);
            hA[r * PK + d * 64 + i]      = (_Float16)__builtin_amdgcn_sinf(rev);
            hA[r * PK + d * 64 + 32 + i] = (_Float16)__builtin_amdgcn_cosf(rev);
        }
    }
    __syncthreads();

    const _Float16* __restrict__ Wp = isPg ? WpC : WpQ;
    _Float16* __restrict__ out = isPg ? pg : pq;

    f32x4 acc[2][6];
    #pragma unroll
    for (int nt = 0; nt < 6; ++nt) {
        f32x4 bv = isPg ? *(const f32x4*)(bc + w * 96 + nt * 16 + lq * 4)
                        : (f32x4){0.f, 0.f, 0.f, 0.f};
        #pragma unroll
        for (int mt = 0; mt < 2; ++mt) acc[mt][nt] = bv;
    }
    #pragma unroll 2
    for (int ks = 0; ks < 6; ++ks) {
        half8 a[2], bf[6];
        #pragma unroll
        for (int mt = 0; mt < 2; ++mt)
            a[mt] = *(const half8*)(hA + (mt * 16 + ln) * PK + ks * 32 + lq * 8);
        #pragma unroll
        for (int nt = 0; nt < 6; ++nt)
            bf[nt] = *(const half8*)(Wp + (size_t)(((w * 6 + nt) * 6 + ks) * 512 + lane * 8));
        #pragma unroll
        for (int nt = 0; nt < 6; ++nt)
            #pragma unroll
            for (int mt = 0; mt < 2; ++mt)
                acc[mt][nt] = __builtin_amdgcn_mfma_f32_16x16x32_f16(bf[nt], a[mt], acc[mt][nt], 0, 0, 0);
    }
    #pragma unroll
    for (int mt = 0; mt < 2; ++mt)
        #pragma unroll
        for (int nt = 0; nt < 6; ++nt) {
            half4v hv;
            #pragma unroll
            for (int r = 0; r < 4; ++r) hv[r] = (_Float16)acc[mt][nt][r];
            *(half4v*)(out + (size_t)(r0 + mt * 16 + ln) * 384 + w * 96 + nt * 16 + lq * 4) = hv;
        }
}

// ---------------- fused edge MLP (layers 1,2) via f16 MFMA, 512 thr / 8 waves --------
#define PADK 392   // hA row stride in f16 elements (784 B)
#define H2S  196   // h2 (f32 view) row stride; conflict-free b128

__global__ __launch_bounds__(512, 6) void edge_mlp_kernel(
    const _Float16* __restrict__ pg, const _Float16* __restrict__ pq,
    const int* __restrict__ edges,
    const _Float16* __restrict__ Wp1, const float* __restrict__ b1,
    const _Float16* __restrict__ Wp2, const float* __restrict__ b2,
    float* __restrict__ seg, float* __restrict__ cnt)
{
    __shared__ _Float16 hA[64 * PADK];   // 50176 B; aliased as f32 h2[64][H2S] later
    __shared__ int qi[64];
    float* h2 = (float*)hA;

    const int t = threadIdx.x;
    const int e0 = blockIdx.x * 64;
    const int lane = t & 63;
    const int w = t >> 6;                // 0..7
    const int ln = lane & 15;
    const int lq = lane >> 4;

    if (t < 64) qi[t] = edges[2 * (e0 + t)];

    // ---- gather h0 = gelu(pg[g] + pq[q]); thread t owns edge m=t>>3, chunk lane t&7 --
    {
        const int m = t >> 3;            // 0..63
        const int cl = t & 7;
        int2 eg = ((const int2*)edges)[e0 + m];     // {qidx, gidx}
        const half8* gsrc = (const half8*)(pg + (size_t)eg.y * 384) + cl;
        const half8* qsrc = (const half8*)(pq + (size_t)eg.x * 384) + cl;
        half8* dst = (half8*)(hA + m * PADK + cl * 8);
        #pragma unroll
        for (int i = 0; i < 6; ++i) {
            half8 va = gsrc[i * 8];
            half8 vb = qsrc[i * 8];
            half8 o;
            #pragma unroll
            for (int j = 0; j < 8; ++j)
                o[j] = (_Float16)gelu_f((float)va[j] + (float)vb[j]);
            dst[i * 8] = o;
        }
    }
    __syncthreads();

    // ---- layer 1: 384 -> 384, gelu, in-place. wave w owns 48-col output slice ----
    {
        f32x4 acc[4][3];
        #pragma unroll
        for (int nt = 0; nt < 3; ++nt) {
            f32x4 bv = *(const f32x4*)(b1 + w * 48 + nt * 16 + lq * 4);
            #pragma unroll
            for (int mt = 0; mt < 4; ++mt) acc[mt][nt] = bv;
        }
        #pragma unroll 2
        for (int ks = 0; ks < 12; ++ks) {
            half8 a[4], bf[3];
            #pragma unroll
            for (int mt = 0; mt < 4; ++mt)
                a[mt] = *(const half8*)(hA + (mt * 16 + ln) * PADK + ks * 32 + lq * 8);
            #pragma unroll
            for (int nt = 0; nt < 3; ++nt)
                bf[nt] = *(const half8*)(Wp1 + (size_t)(((w * 3 + nt) * 12 + ks) * 512 + lane * 8));
            #pragma unroll
            for (int nt = 0; nt < 3; ++nt)
                #pragma unroll
                for (int mt = 0; mt < 4; ++mt)
                    acc[mt][nt] = __builtin_amdgcn_mfma_f32_16x16x32_f16(bf[nt], a[mt], acc[mt][nt], 0, 0, 0);
        }
        __syncthreads();   // all waves done reading hA
        // lane holds h[m = mt*16+ln][n = w*48 + nt*16 + lq*4 + r] -> packed b64 writes
        #pragma unroll
        for (int mt = 0; mt < 4; ++mt)
            #pragma unroll
            for (int nt = 0; nt < 3; ++nt) {
                half4v hv;
                #pragma unroll
                for (int r = 0; r < 4; ++r) hv[r] = (_Float16)gelu_f(acc[mt][nt][r]);
                *(half4v*)(hA + (mt * 16 + ln) * PADK + w * 48 + nt * 16 + lq * 4) = hv;
            }
        __syncthreads();
    }

    // ---- layer 2: 384 -> 192. wave w: n-slice (w&3)*48, m-half (w>>2)*32 ----
    {
        const int n0 = (w & 3) * 48;
        const int mh = (w >> 2) * 2;                 // physical m-tile base
        f32x4 acc[2][3];
        #pragma unroll
        for (int nt = 0; nt < 3; ++nt) {
            f32x4 bv = *(const f32x4*)(b2 + n0 + nt * 16 + lq * 4);
            #pragma unroll
            for (int mt = 0; mt < 2; ++mt) acc[mt][nt] = bv;
        }
        #pragma unroll 2
        for (int ks = 0; ks < 12; ++ks) {
            half8 a[2], bf[3];
            #pragma unroll
            for (int mt = 0; mt < 2; ++mt)
                a[mt] = *(const half8*)(hA + ((mh + mt) * 16 + ln) * PADK + ks * 32 + lq * 8);
            #pragma unroll
            for (int nt = 0; nt < 3; ++nt)
                bf[nt] = *(const half8*)(Wp2 + (size_t)((((w & 3) * 3 + nt) * 12 + ks) * 512 + lane * 8));
            #pragma unroll
            for (int nt = 0; nt < 3; ++nt)
                #pragma unroll
                for (int mt = 0; mt < 2; ++mt)
                    acc[mt][nt] = __builtin_amdgcn_mfma_f32_16x16x32_f16(bf[nt], a[mt], acc[mt][nt], 0, 0, 0);
        }
        __syncthreads();   // all waves done reading hA; safe to overwrite as h2
        #pragma unroll
        for (int mt = 0; mt < 2; ++mt)
            #pragma unroll
            for (int nt = 0; nt < 3; ++nt)
                *(f32x4*)(h2 + ((mh + mt) * 16 + ln) * H2S + n0 + nt * 16 + lq * 4) = acc[mt][nt];
        __syncthreads();
    }

    // ---- segment reduce within block (qidx sorted), 2 row-halves, then atomics ----
    if (t < 384) {
        int half_ = t >= 192;
        int col = t - half_ * 192;
        int mlo = half_ * 32, mhi = mlo + 32;
        float a = 0.0f;
        for (int m = mlo; m < mhi; ++m) {
            a += h2[m * H2S + col];
            if (m == mhi - 1 || qi[m + 1] != qi[m]) {
                atomicAdd(&seg[(size_t)qi[m] * 192 + col], a);
                a = 0.0f;
            }
        }
    } else if (t < 386) {
        int half_ = t - 384;
        int mlo = half_ * 32, mhi = mlo + 32;
        float run = 1.0f;
        for (int m = mlo + 1; m < mhi; ++m) {
            if (qi[m] != qi[m - 1]) { atomicAdd(&cnt[qi[m - 1]], run); run = 1.0f; }
            else run += 1.0f;
        }
        atomicAdd(&cnt[qi[mhi - 1]], run);
    }
}

// ---------------- head: m = seg/max(cnt,1); out = gelu(m@W0+b0)@W1+b1 ----------------
#define PSK 196   // ps row stride (f32)

__global__ __launch_bounds__(256, 3) void head_kernel(
    const float* __restrict__ seg, const float* __restrict__ cnt,
    const _Float16* __restrict__ Wp0, const float* __restrict__ b0,
    const float* __restrict__ w1, const float* __restrict__ b1,
    float* __restrict__ out)
{
    __shared__ _Float16 hA[32 * PK];     // 12800 B
    __shared__ float ps[32 * PSK];       // 25088 B
    __shared__ float w1s[192 * 4];
    __shared__ float invc[32];
    const int t = threadIdx.x;
    const int r0 = blockIdx.x * 32;
    const int lane = t & 63;
    const int w = t >> 6;
    const int ln = lane & 15, lq = lane >> 4;

    if (t < 32) invc[t] = 1.0f / fmaxf(cnt[r0 + t], 1.0f);
    if (t < 192) ((float4*)w1s)[t] = ((const float4*)w1)[t];
    __syncthreads();

    #pragma unroll
    for (int i = 0; i < 6; ++i) {                    // 1536 float4s
        int idx = t + 256 * i;
        int r = idx / 48, c4 = idx - r * 48;
        float inv = invc[r];
        float4 v = ((const float4*)(seg + (size_t)(r0 + r) * 192))[c4];
        half4v hv; hv[0] = (_Float16)(v.x * inv); hv[1] = (_Float16)(v.y * inv);
        hv[2] = (_Float16)(v.z * inv); hv[3] = (_Float16)(v.w * inv);
        *(half4v*)(hA + r * PK + c4 * 4) = hv;
    }
    __syncthreads();

    f32x4 acc[2][3];
    #pragma unroll
    for (int nt = 0; nt < 3; ++nt) {
        f32x4 bv = *(const f32x4*)(b0 + w * 48 + nt * 16 + lq * 4);
        #pragma unroll
        for (int mt = 0; mt < 2; ++mt) acc[mt][nt] = bv;
    }
    #pragma unroll 2
    for (int ks = 0; ks < 6; ++ks) {
        half8 a[2], bf[3];
        #pragma unroll
        for (int mt = 0; mt < 2; ++mt)
            a[mt] = *(const half8*)(hA + (mt * 16 + ln) * PK + ks * 32 + lq * 8);
        #pragma unroll
        for (int nt = 0; nt < 3; ++nt)
            bf[nt] = *(const half8*)(Wp0 + (size_t)(((w * 3 + nt) * 6 + ks) * 512 + lane * 8));
        #pragma unroll
        for (int nt = 0; nt < 3; ++nt)
            #pragma unroll
            for (int mt = 0; mt < 2; ++mt)
                acc[mt][nt] = __builtin_amdgcn_mfma_f32_16x16x32_f16(bf[nt], a[mt], acc[mt][nt], 0, 0, 0);
    }
    // lane holds ps[m = mt*16+ln][n = w*48 + nt*16 + lq*4 + r] -> b128 LDS writes
    #pragma unroll
    for (int mt = 0; mt < 2; ++mt)
        #pragma unroll
        for (int nt = 0; nt < 3; ++nt) {
            f32x4 g;
            #pragma unroll
            for (int r = 0; r < 4; ++r) g[r] = gelu_f(acc[mt][nt][r]);
            *(f32x4*)(ps + (mt * 16 + ln) * PSK + w * 48 + nt * 16 + lq * 4) = g;
        }
    __syncthreads();

    // layer1: 192 -> 4, one thread per (row, out-col); rows 0..31
    if (t < 128) {
        int r = t >> 2, oo = t & 3;
        float a = b1[oo];
        for (int k = 0; k < 192; ++k)
            a = fmaf(ps[r * PSK + k], w1s[k * 4 + oo], a);
        out[(size_t)(r0 + r) * 4 + oo] = a;
    }
}

extern "C" void kernel_launch(void* const* d_in, const int* in_sizes, int n_in,
                              void* d_out, int out_size, void* d_ws, size_t ws_size,
                              hipStream_t stream) {
    (void)in_sizes; (void)n_in; (void)out_size; (void)ws_size;
    const float* x       = (const float*)d_in[0];
    const float* qpos    = (const float*)d_in[1];
    const int*   edges   = (const int*)d_in[2];
    const float* proj_w  = (const float*)d_in[3];
    const float* proj_b  = (const float*)d_in[4];
    const float* msg0_w  = (const float*)d_in[5];
    const float* msg0_b  = (const float*)d_in[6];
    const float* msg1_w  = (const float*)d_in[7];
    const float* msg1_b  = (const float*)d_in[8];
    const float* msg2_w  = (const float*)d_in[9];
    const float* msg2_b  = (const float*)d_in[10];
    const float* pred0_w = (const float*)d_in[11];
    const float* pred0_b = (const float*)d_in[12];
    const float* pred1_w = (const float*)d_in[13];
    const float* pred1_b = (const float*)d_in[14];
    float* out = (float*)d_out;

    // ws layout (bytes):
    //  pg  f16: 25165824  @ 0
    //  pq  f16: 25165824  @ 25165824
    //  seg f32: 25165824  @ 50331648
    //  cnt f32:   131072  @ 75497472   (seg+cnt zeroed by pgpq zero-blocks)
    //  bc  f32:     1536  @ 75628544
    //  WpC f16:   147456  @ 75630080
    //  WpQ f16:   147456  @ 75777536
    //  Wp1 f16:   294912  @ 75924992
    //  Wp2 f16:   147456  @ 76219904
    //  WpH f16:    73728  @ 76367360   (end 76441088)
    char* ws = (char*)d_ws;
    _Float16* pg  = (_Float16*)(ws);
    _Float16* pq  = (_Float16*)(ws + 25165824);
    float*    seg = (float*)(ws + 50331648);
    float*    cnt = (float*)(ws + 75497472);
    float*    bc  = (float*)(ws + 75628544);
    _Float16* WpC = (_Float16*)(ws + 75630080);
    _Float16* WpQ = (_Float16*)(ws + 75777536);
    _Float16* Wp1 = (_Float16*)(ws + 75924992);
    _Float16* Wp2 = (_Float16*)(ws + 76219904);
    _Float16* WpH = (_Float16*)(ws + 76367360);

    preppack_kernel<<<452, 256, 0, stream>>>(proj_w, proj_b, msg0_w, msg0_b,
                                             msg1_w, msg2_w, pred0_w,
                                             WpC, bc, WpQ, Wp1, Wp2, WpH);
    // 2048 GEMM blocks + 386 zero-blocks (25296896 B = seg+cnt, 65536 B each)
    pgpq_kernel<<<2434, 256, 0, stream>>>(x, qpos, WpC, WpQ, bc, pg, pq, seg);
    edge_mlp_kernel<<<4096, 512, 0, stream>>>(pg, pq, edges,
                                              Wp1, msg1_b, Wp2, msg2_b,
                                              seg, cnt);
    head_kernel<<<1024, 256, 0, stream>>>(seg, cnt, WpH, pred0_b,
                                          pred1_w, pred1_b, out);
}